// Round 1
// baseline (461.415 us; speedup 1.0000x reference)
//
#include <hip/hip_runtime.h>

// Problem constants (from reference setup_inputs)
constexpr int B = 32, P = 3, C = 512, N = 1024;
constexpr int G = B * P;            // 96 (b,p) groups
constexpr int CSPLIT = 8;           // split C across blocks: 96*8 = 768 blocks = 3/CU
constexpr int CCHUNK = C / CSPLIT;  // 64 c-iterations per block

// Layout: x[(g*C + c)*N + n], g = b*P + p. n contiguous -> lanes along n.
// out[(g*N + n)*3 + {0,1,2}] = {l1, sq_l2, l1}
__global__ __launch_bounds__(256) void dist_partial_kernel(
    const float* __restrict__ x1, const float* __restrict__ x2,
    float* __restrict__ out)
{
    const int g     = blockIdx.x / CSPLIT;
    const int chunk = blockIdx.x % CSPLIT;
    const int t     = threadIdx.x;          // 0..255, handles n = 4t .. 4t+3

    const float4* a = (const float4*)(x1 + (size_t)g * C * N) + t;
    const float4* b = (const float4*)(x2 + (size_t)g * C * N) + t;
    const int c0 = chunk * CCHUNK;

    float4 l1 = make_float4(0.f, 0.f, 0.f, 0.f);
    float4 l2 = make_float4(0.f, 0.f, 0.f, 0.f);

    #pragma unroll 4
    for (int c = c0; c < c0 + CCHUNK; ++c) {
        const float4 av = a[(size_t)c * (N / 4)];
        const float4 bv = b[(size_t)c * (N / 4)];
        const float dx = av.x - bv.x;
        const float dy = av.y - bv.y;
        const float dz = av.z - bv.z;
        const float dw = av.w - bv.w;
        l1.x += fabsf(dx); l1.y += fabsf(dy); l1.z += fabsf(dz); l1.w += fabsf(dw);
        l2.x = fmaf(dx, dx, l2.x); l2.y = fmaf(dy, dy, l2.y);
        l2.z = fmaf(dz, dz, l2.z); l2.w = fmaf(dw, dw, l2.w);
    }

    const size_t obase = ((size_t)g * N + 4 * (size_t)t) * 3;
    const float l1v[4] = {l1.x, l1.y, l1.z, l1.w};
    const float l2v[4] = {l2.x, l2.y, l2.z, l2.w};
    #pragma unroll
    for (int i = 0; i < 4; ++i) {
        atomicAdd(&out[obase + 3 * i + 0], l1v[i]);
        atomicAdd(&out[obase + 3 * i + 1], l2v[i]);
        atomicAdd(&out[obase + 3 * i + 2], l1v[i]);
    }
}

extern "C" void kernel_launch(void* const* d_in, const int* in_sizes, int n_in,
                              void* d_out, int out_size, void* d_ws, size_t ws_size,
                              hipStream_t stream) {
    const float* x1 = (const float*)d_in[0];
    const float* x2 = (const float*)d_in[1];
    float* out = (float*)d_out;

    // d_out is re-poisoned to 0xAA before every timed launch; atomics need zeros.
    hipMemsetAsync(d_out, 0, (size_t)out_size * sizeof(float), stream);

    dist_partial_kernel<<<G * CSPLIT, 256, 0, stream>>>(x1, x2, out);
}

// Round 2
// 392.551 us; speedup vs baseline: 1.1754x; 1.1754x over previous
//
#include <hip/hip_runtime.h>

// Problem constants (from reference setup_inputs)
constexpr int B = 32, P = 3, C = 512, N = 1024;
constexpr int G = B * P;             // 96 (b,p) groups
constexpr int CSPLIT = 16;           // 96*16 = 1536 blocks = 6 blocks/CU (75% occ)
constexpr int CCHUNK = C / CSPLIT;   // 32 c-iterations per block
constexpr size_t WS_NEED = (size_t)CSPLIT * G * N * 2 * sizeof(float); // 12.6 MB

// ---- Kernel 1: partial L1/L2 over a 32-c chunk. No atomics; coalesced float4
// stores of (l1,l2) pairs into ws laid out [chunk][g][n] (float2 per n).
__global__ __launch_bounds__(256) void dist_partial(
    const float* __restrict__ x1, const float* __restrict__ x2,
    float* __restrict__ ws)
{
    const int g     = blockIdx.x / CSPLIT;
    const int chunk = blockIdx.x % CSPLIT;
    const int t     = threadIdx.x;            // owns n = 4t..4t+3

    const float4* pa = (const float4*)(x1 + (size_t)g * C * N)
                       + (size_t)chunk * CCHUNK * (N / 4) + t;
    const float4* pb = (const float4*)(x2 + (size_t)g * C * N)
                       + (size_t)chunk * CCHUNK * (N / 4) + t;

    float4 l1 = make_float4(0.f, 0.f, 0.f, 0.f);
    float4 l2 = make_float4(0.f, 0.f, 0.f, 0.f);

    // Grouped loads: 8 independent float4 loads issued before any use so the
    // compiler keeps them in flight (needs ~32 data VGPRs -> forces pipelining).
    #pragma unroll
    for (int j = 0; j < CCHUNK; j += 4) {
        const float4 a0 = pa[0 * (N / 4)];
        const float4 a1 = pa[1 * (N / 4)];
        const float4 a2 = pa[2 * (N / 4)];
        const float4 a3 = pa[3 * (N / 4)];
        const float4 b0 = pb[0 * (N / 4)];
        const float4 b1 = pb[1 * (N / 4)];
        const float4 b2 = pb[2 * (N / 4)];
        const float4 b3 = pb[3 * (N / 4)];
        pa += N;  // 4 rows in float4 units
        pb += N;
        float d;
        d = a0.x - b0.x; l1.x += fabsf(d); l2.x = fmaf(d, d, l2.x);
        d = a0.y - b0.y; l1.y += fabsf(d); l2.y = fmaf(d, d, l2.y);
        d = a0.z - b0.z; l1.z += fabsf(d); l2.z = fmaf(d, d, l2.z);
        d = a0.w - b0.w; l1.w += fabsf(d); l2.w = fmaf(d, d, l2.w);
        d = a1.x - b1.x; l1.x += fabsf(d); l2.x = fmaf(d, d, l2.x);
        d = a1.y - b1.y; l1.y += fabsf(d); l2.y = fmaf(d, d, l2.y);
        d = a1.z - b1.z; l1.z += fabsf(d); l2.z = fmaf(d, d, l2.z);
        d = a1.w - b1.w; l1.w += fabsf(d); l2.w = fmaf(d, d, l2.w);
        d = a2.x - b2.x; l1.x += fabsf(d); l2.x = fmaf(d, d, l2.x);
        d = a2.y - b2.y; l1.y += fabsf(d); l2.y = fmaf(d, d, l2.y);
        d = a2.z - b2.z; l1.z += fabsf(d); l2.z = fmaf(d, d, l2.z);
        d = a2.w - b2.w; l1.w += fabsf(d); l2.w = fmaf(d, d, l2.w);
        d = a3.x - b3.x; l1.x += fabsf(d); l2.x = fmaf(d, d, l2.x);
        d = a3.y - b3.y; l1.y += fabsf(d); l2.y = fmaf(d, d, l2.y);
        d = a3.z - b3.z; l1.z += fabsf(d); l2.z = fmaf(d, d, l2.z);
        d = a3.w - b3.w; l1.w += fabsf(d); l2.w = fmaf(d, d, l2.w);
    }

    // ws layout: float2 ws2[(chunk*G + g)*N + n] = (l1, l2). Thread writes
    // 4 consecutive float2 = 32 B -> two float4 stores, wave-contiguous 2 KB.
    float4* wout = (float4*)ws + ((size_t)(chunk * G + g) * N) / 2 + 2 * t;
    wout[0] = make_float4(l1.x, l2.x, l1.y, l2.y);
    wout[1] = make_float4(l1.z, l2.z, l1.w, l2.w);
}

// ---- Kernel 2: combine 16 partials per (g,n), emit [l1, sq_l2, l1].
__global__ __launch_bounds__(256) void dist_combine(
    const float* __restrict__ ws, float* __restrict__ out)
{
    const int idx = blockIdx.x * 256 + threadIdx.x;   // (g,n) flat, 0..98303
    const float2* ws2 = (const float2*)ws;
    float l1 = 0.f, l2 = 0.f;
    #pragma unroll
    for (int chunk = 0; chunk < CSPLIT; ++chunk) {
        const float2 v = ws2[(size_t)chunk * G * N + idx];
        l1 += v.x;
        l2 += v.y;
    }
    out[3 * (size_t)idx + 0] = l1;
    out[3 * (size_t)idx + 1] = l2;
    out[3 * (size_t)idx + 2] = l1;
}

// ---- Fallback (ws too small): original atomic path, correctness-safe.
__global__ __launch_bounds__(256) void dist_atomic(
    const float* __restrict__ x1, const float* __restrict__ x2,
    float* __restrict__ out)
{
    const int g     = blockIdx.x / CSPLIT;
    const int chunk = blockIdx.x % CSPLIT;
    const int t     = threadIdx.x;
    const float4* a = (const float4*)(x1 + (size_t)g * C * N) + t;
    const float4* b = (const float4*)(x2 + (size_t)g * C * N) + t;
    const int c0 = chunk * CCHUNK;
    float4 l1 = make_float4(0.f, 0.f, 0.f, 0.f);
    float4 l2 = make_float4(0.f, 0.f, 0.f, 0.f);
    for (int c = c0; c < c0 + CCHUNK; ++c) {
        const float4 av = a[(size_t)c * (N / 4)];
        const float4 bv = b[(size_t)c * (N / 4)];
        float d;
        d = av.x - bv.x; l1.x += fabsf(d); l2.x = fmaf(d, d, l2.x);
        d = av.y - bv.y; l1.y += fabsf(d); l2.y = fmaf(d, d, l2.y);
        d = av.z - bv.z; l1.z += fabsf(d); l2.z = fmaf(d, d, l2.z);
        d = av.w - bv.w; l1.w += fabsf(d); l2.w = fmaf(d, d, l2.w);
    }
    const size_t obase = ((size_t)g * N + 4 * (size_t)t) * 3;
    const float l1v[4] = {l1.x, l1.y, l1.z, l1.w};
    const float l2v[4] = {l2.x, l2.y, l2.z, l2.w};
    #pragma unroll
    for (int i = 0; i < 4; ++i) {
        atomicAdd(&out[obase + 3 * i + 0], l1v[i]);
        atomicAdd(&out[obase + 3 * i + 1], l2v[i]);
        atomicAdd(&out[obase + 3 * i + 2], l1v[i]);
    }
}

extern "C" void kernel_launch(void* const* d_in, const int* in_sizes, int n_in,
                              void* d_out, int out_size, void* d_ws, size_t ws_size,
                              hipStream_t stream) {
    const float* x1 = (const float*)d_in[0];
    const float* x2 = (const float*)d_in[1];
    float* out = (float*)d_out;

    if (ws_size >= WS_NEED) {
        dist_partial<<<G * CSPLIT, 256, 0, stream>>>(x1, x2, (float*)d_ws);
        dist_combine<<<(G * N) / 256, 256, 0, stream>>>((const float*)d_ws, out);
    } else {
        hipMemsetAsync(d_out, 0, (size_t)out_size * sizeof(float), stream);
        dist_atomic<<<G * CSPLIT, 256, 0, stream>>>(x1, x2, out);
    }
}